// Round 9
// baseline (181.548 us; speedup 1.0000x reference)
//
#include <hip/hip_runtime.h>
#include <hip/hip_bf16.h>
#include <stdint.h>

typedef _Float16 f16_t;
typedef f16_t f16x8 __attribute__((ext_vector_type(8)));
typedef float f32x4 __attribute__((ext_vector_type(4)));

// lgkm-only barrier: 0xC07F = vmcnt(63) expcnt(7) lgkmcnt(0).
__device__ inline void lgkm_barrier() {
    __builtin_amdgcn_s_waitcnt(0xC07F);
    __builtin_amdgcn_s_barrier();
}

// ---------------------------------------------------------------------------
// Single fused kernel, manual ticket barrier (NO cooperative API).
// Grid 256 x 1024, 132 KB LDS -> exactly 1 block/CU -> all 256 blocks are
// co-resident by construction, so a device-scope atomic barrier is safe.
// Phase 1: each block transposes 2 (b,y) rows of x -> xt (NHWC f16) and
//          packs weights for o = blk -> Wp (conflict-free tile layout);
//          sT corner table built concurrently (reads only coff/cwm).
// Barrier: release-fence + ticket atomicAdd; spin until 256 (BOUNDED: on
//          timeout proceed -> wrong answer, NOT a hang).
// Phase 2: r5's proven k_dcn body (60.1 us): reg-staged A into LDS,
//          96 KB vmem/iter/CU, conflict-free sA, lgkm-only barriers.
// ---------------------------------------------------------------------------
__global__ __launch_bounds__(1024, 4) void k_all(
    const float* __restrict__ x, const float* __restrict__ w,
    const float* __restrict__ coff, const float* __restrict__ cwm,
    const float* __restrict__ bias, float* __restrict__ out,
    f16_t* __restrict__ xt, f16_t* __restrict__ Wp,
    unsigned int* __restrict__ ctr) {

    __shared__ __align__(16) f16_t sS[2][128 * 64];   // 32 KB sampled tile
    __shared__ __align__(16) f16_t sA[2][16384];      // 64 KB A double-buffer
    __shared__ __align__(16) int2 sT[9 * 128 * 4];    // 36 KB corner table

    const int blk = blockIdx.x;
    const int t = threadIdx.x;

    // ================= phase 1a: transpose 2 rows =================
    {
        const int task = blk * 2 + (t >> 9);      // 0..511
        const int u = t & 511;
        const int tb = task >> 6;                 // batch
        const int ty = task & 63;                 // row
        const float* src = x + ((size_t)(tb * 256) * 64 + ty) * 64;
        const int x4 = (u & 15) * 4;
        const int c0 = (u >> 4) * 8;
        float4 v[8];
#pragma unroll
        for (int e = 0; e < 8; ++e)
            v[e] = *(const float4*)(src + (size_t)(c0 + e) * 4096 + x4);
        f16_t* dst = xt + ((size_t)(tb * 64 + ty) * 64) * 256;
#pragma unroll
        for (int j = 0; j < 4; ++j) {
            f16x8 o;
#pragma unroll
            for (int e = 0; e < 8; ++e) {
                const float f = (j == 0) ? v[e].x : (j == 1) ? v[e].y
                              : (j == 2) ? v[e].z : v[e].w;
                o[e] = (f16_t)f;
            }
            *(f16x8*)(dst + (x4 + j) * 256 + c0) = o;
        }
    }
    // ================= phase 1b: weight pack for o = blk =================
    if (t < 288) {
        const int o = blk;
        const int kb2 = t >> 3, rr = t & 7;
        const int s = rr >> 2, qq = rr & 3;
        const int kk = kb2 >> 2, cp = kb2 & 3;
        f16x8 vv;
#pragma unroll
        for (int e = 0; e < 8; ++e) {
            const int c = cp * 64 + s * 32 + qq * 8 + e;
            vv[e] = (f16_t)w[(size_t)o * 2304 + c * 9 + kk];
        }
        *(f16x8*)(Wp + (size_t)kb2 * 16384 + s * 8192 + qq * 2048
                      + (size_t)o * 8) = vv;
    }

    // ---- DCN mapping ----
    const int b  = blk & 7;        // XCD pin
    const int hb = blk >> 3;
    const int h0 = hb * 2;
    const int wv = t >> 6;
    const int lane = t & 63;
    const int mg = wv >> 1;        // 0..7 : M-group (32 O rows)
    const int ng = wv & 1;         // 0..1 : h-row

    const int p = t >> 3;          // 0..127 pixel
    const int q = t & 7;           // 8-channel slice

    const int fr = lane & 15;
    const int quad = lane >> 4;
    const int swz = fr & 7;

    // ---- sT corner table (reads only coff/cwm): hides before the barrier --
    for (int u = t; u < 1152; u += 1024) {
        const int kk = u >> 7, pp = u & 127;
        const int hr = pp >> 6, wpx = pp & 63;
        const int h = h0 + hr;
        float oy = coff[((size_t)(b * 18 + kk * 2 + 0) * 64 + h) * 64 + wpx];
        float ox = coff[((size_t)(b * 18 + kk * 2 + 1) * 64 + h) * 64 + wpx];
        float m  = cwm [((size_t)(b * 9 + kk) * 64 + h) * 64 + wpx];
        float py = (float)(h - 1 + (kk / 3)) + oy;
        float px = (float)(wpx - 1 + (kk % 3)) + ox;
        float fy = floorf(py), fx = floorf(px);
        int y0 = (int)fy, x0 = (int)fx;
        int y1 = y0 + 1,  x1 = x0 + 1;
        float wy1 = py - fy, wx1 = px - fx;
        float wy0 = 1.0f - wy1, wx0 = 1.0f - wx1;
        bool vy0 = (y0 >= 0) && (y0 < 64), vy1 = (y1 >= 0) && (y1 < 64);
        bool vx0 = (x0 >= 0) && (x0 < 64), vx1 = (x1 >= 0) && (x1 < 64);
        int yc0 = min(max(y0, 0), 63), yc1 = min(max(y1, 0), 63);
        int xc0 = min(max(x0, 0), 63), xc1 = min(max(x1, 0), 63);
        const int base = b * 4096;
        float cw[4];
        int   ca[4];
        cw[0] = (vy0 && vx0) ? wy0 * wx0 * m : 0.0f;
        cw[1] = (vy0 && vx1) ? wy0 * wx1 * m : 0.0f;
        cw[2] = (vy1 && vx0) ? wy1 * wx0 * m : 0.0f;
        cw[3] = (vy1 && vx1) ? wy1 * wx1 * m : 0.0f;
        ca[0] = (base + yc0 * 64 + xc0) * 512;
        ca[1] = (base + yc0 * 64 + xc1) * 512;
        ca[2] = (base + yc1 * 64 + xc0) * 512;
        ca[3] = (base + yc1 * 64 + xc1) * 512;
#pragma unroll
        for (int c = 0; c < 4; ++c) {
            unsigned short ws = __builtin_bit_cast(unsigned short, (f16_t)cw[c]);
            sT[(kk * 128 + pp) * 4 + c] = make_int2(ca[c], (int)ws);
        }
    }

    // ================= grid ticket barrier (bounded spin) =================
    __syncthreads();                      // all block stores drained (vmcnt 0)
    if (t == 0) {
        __threadfence();                  // device-scope release of xt/Wp
        __hip_atomic_fetch_add(ctr, 1u, __ATOMIC_ACQ_REL,
                               __HIP_MEMORY_SCOPE_AGENT);
        int budget = 1 << 22;             // ~tens of ms >> prep time: no hang
        while (__hip_atomic_load(ctr, __ATOMIC_ACQUIRE,
                                 __HIP_MEMORY_SCOPE_AGENT) < 256u && --budget)
            __builtin_amdgcn_s_sleep(8);
        __threadfence();                  // acquire side
    }
    __syncthreads();                      // release whole block

    // ================= phase 2: fused sample + GEMM (r5 body) =============
    f16_t* const swb0 = &sS[0][p * 64 + ((q ^ (p & 7)) * 8)];
    const int qb = q * 16;
    const char* xb = (const char*)xt;

    f32x4 acc[2][4] = {};
    f16x8 g0, g1, g2, g3;
    f16x8 sld0, sld1;
    int4 t0, t1;

    auto stage_load = [&](int it) {
        const f16_t* g = Wp + (size_t)it * 16384 + wv * 1024 + lane * 8;
        sld0 = *(const f16x8*)(g);
        sld1 = *(const f16x8*)(g + 512);
    };
    auto stage_write = [&](int buf) {
        f16_t* l = &sA[buf][wv * 1024 + lane * 8];
        *(f16x8*)(l)       = sld0;
        *(f16x8*)(l + 512) = sld1;
    };

    auto gather_issue = [&](int it) {
        const int kk = it >> 2, cp = it & 3;
        if ((it & 3) == 0) {
            const int4* tp = (const int4*)&sT[(kk * 128 + p) * 4];
            t0 = tp[0];
            t1 = tp[1];
        }
        const int cb = cp * 128 + qb;
        g0 = *(const f16x8*)(xb + (t0.x + cb));
        g1 = *(const f16x8*)(xb + (t0.z + cb));
        g2 = *(const f16x8*)(xb + (t1.x + cb));
        g3 = *(const f16x8*)(xb + (t1.z + cb));
    };

    auto combine_write = [&](int buf) {
        f16_t w0 = __builtin_bit_cast(f16_t, (unsigned short)t0.y);
        f16_t w1 = __builtin_bit_cast(f16_t, (unsigned short)t0.w);
        f16_t w2 = __builtin_bit_cast(f16_t, (unsigned short)t1.y);
        f16_t w3 = __builtin_bit_cast(f16_t, (unsigned short)t1.w);
        f16x8 w0v = {w0, w0, w0, w0, w0, w0, w0, w0};
        f16x8 w1v = {w1, w1, w1, w1, w1, w1, w1, w1};
        f16x8 w2v = {w2, w2, w2, w2, w2, w2, w2, w2};
        f16x8 w3v = {w3, w3, w3, w3, w3, w3, w3, w3};
        f16x8 ov = g0 * w0v + g1 * w1v + g2 * w2v + g3 * w3v;
        *(f16x8*)(swb0 + buf * 8192) = ov;
    };

    auto do_mfma = [&](int cur) {
        const f16_t* sb = &sS[cur][ng * 4096];
        const f16_t* sa = &sA[cur][quad * 2048 + mg * 256 + fr * 8];
        f16x8 aC[2][2];
        aC[0][0] = *(const f16x8*)(sa);
        aC[0][1] = *(const f16x8*)(sa + 8192);
        aC[1][0] = *(const f16x8*)(sa + 128);
        aC[1][1] = *(const f16x8*)(sa + 8192 + 128);
        __builtin_amdgcn_s_setprio(1);
#pragma unroll
        for (int s = 0; s < 2; ++s) {
            const int coffe = ((s * 4 + quad) ^ swz) * 8;
            f16x8 bb[4];
#pragma unroll
            for (int nt = 0; nt < 4; ++nt)
                bb[nt] = *(const f16x8*)(sb + (nt * 16 + fr) * 64 + coffe);
#pragma unroll
            for (int mt = 0; mt < 2; ++mt)
#pragma unroll
                for (int nt = 0; nt < 4; ++nt)
                    acc[mt][nt] = __builtin_amdgcn_mfma_f32_16x16x32_f16(
                        aC[mt][s], bb[nt], acc[mt][nt], 0, 0, 0);
        }
        __builtin_amdgcn_s_setprio(0);
    };

    // ---- prologue ----
    stage_load(0);
    gather_issue(0);
    combine_write(0);
    stage_write(0);
    lgkm_barrier();

    // ---- main loop: 18 x 2 phases ----
    for (int it2 = 0; it2 < 36; it2 += 2) {
        stage_load(it2 + 1);
        gather_issue(it2 + 1);
        __builtin_amdgcn_sched_barrier(0);
        do_mfma(0);
        __builtin_amdgcn_sched_barrier(0);
        combine_write(1);
        stage_write(1);
        lgkm_barrier();

        const bool more = (it2 + 2) < 36;
        if (more) {
            stage_load(it2 + 2);
            gather_issue(it2 + 2);
        }
        __builtin_amdgcn_sched_barrier(0);
        do_mfma(1);
        __builtin_amdgcn_sched_barrier(0);
        if (more) {
            combine_write(0);
            stage_write(0);
        }
        lgkm_barrier();
    }

    // ---- epilogue ----
    const int rowq = quad * 4;
#pragma unroll
    for (int mt = 0; mt < 2; ++mt) {
#pragma unroll
        for (int r = 0; r < 4; ++r) {
            const int og = mg * 32 + mt * 16 + rowq + r;
            const float bs = bias[og];
            float* opn = out + ((size_t)(b * 256 + og) * 64 + (h0 + ng)) * 64;
#pragma unroll
            for (int nt = 0; nt < 4; ++nt) {
                opn[nt * 16 + fr] = acc[mt][nt][r] + bs;
            }
        }
    }
}

// ---------------------------------------------------------------------------
extern "C" void kernel_launch(void* const* d_in, const int* in_sizes, int n_in,
                              void* d_out, int out_size, void* d_ws, size_t ws_size,
                              hipStream_t stream) {
    const float* x    = (const float*)d_in[0];  // (8,256,64,64)
    const float* coff = (const float*)d_in[1];  // (8,18,64,64)
    const float* cwm  = (const float*)d_in[2];  // (8,9,64,64)
    const float* wgt  = (const float*)d_in[3];  // (256,256,3,3)
    const float* bias = (const float*)d_in[4];  // (256,)
    float* out = (float*)d_out;                 // (8,256,64,64)

    f16_t* xt = (f16_t*)d_ws;                         // 16.8 MB
    f16_t* Wp = xt + (size_t)8 * 64 * 64 * 256;       // 1.18 MB
    unsigned int* ctr = (unsigned int*)(Wp + (size_t)36 * 16384);

    hipMemsetAsync(ctr, 0, 4, stream);          // captured stream op
    void* args_unused = nullptr; (void)args_unused;
    k_all<<<256, 1024, 0, stream>>>(x, wgt, coff, cwm, bias, out, xt, Wp, ctr);
}

// Round 11
// 144.744 us; speedup vs baseline: 1.2543x; 1.2543x over previous
//
#include <hip/hip_runtime.h>
#include <hip/hip_bf16.h>
#include <stdint.h>

typedef _Float16 f16_t;
typedef f16_t f16x8 __attribute__((ext_vector_type(8)));
typedef float f32x4 __attribute__((ext_vector_type(4)));

// lgkm-only barrier: 0xC07F = vmcnt(63) expcnt(7) lgkmcnt(0).
// Waits LDS ops only; global prefetches stay in flight across the barrier.
__device__ inline void lgkm_barrier() {
    __builtin_amdgcn_s_waitcnt(0xC07F);
    __builtin_amdgcn_s_barrier();
}

// ---------------------------------------------------------------------------
// Kernel 1 (merged prep), 512 threads (r5 verbatim — proven):
//  blocks 0..511  : transpose+cast x(B,C,H,W) f32 -> xt(B,H,W,C) f16.
//  blocks 512..575: pack weight (O,C,3,3) f32 -> Wp f16, conflict-free tile
//    layout: Wp[it*16384 + s*8192 + qq*2048 + o*8 + e], c = cp*64+s*32+qq*8+e.
// ---------------------------------------------------------------------------
__global__ __launch_bounds__(512) void k_prep(const float* __restrict__ x,
                                              const float* __restrict__ w,
                                              f16_t* __restrict__ xt,
                                              f16_t* __restrict__ Wp) {
    __shared__ __align__(16) float lw[9216];      // weight path only (36 KB)
    const int t = threadIdx.x;
    if (blockIdx.x < 512) {
        const int b = blockIdx.x >> 6;
        const int y = blockIdx.x & 63;
        const float* src = x + ((size_t)(b * 256) * 64 + y) * 64;
        const int x4 = (t & 15) * 4;              // 4 x-positions
        const int c0 = (t >> 4) * 8;              // 8 channels
        float4 v[8];
#pragma unroll
        for (int e = 0; e < 8; ++e)
            v[e] = *(const float4*)(src + (size_t)(c0 + e) * 4096 + x4);
        f16_t* dst = xt + ((size_t)(b * 64 + y) * 64) * 256;
#pragma unroll
        for (int j = 0; j < 4; ++j) {
            f16x8 o;
#pragma unroll
            for (int e = 0; e < 8; ++e) {
                const float f = (j == 0) ? v[e].x : (j == 1) ? v[e].y
                              : (j == 2) ? v[e].z : v[e].w;
                o[e] = (f16_t)f;
            }
            *(f16x8*)(dst + (x4 + j) * 256 + c0) = o;   // 16B, 64B-aligned
        }
    } else {
        const int o0 = (blockIdx.x - 512) * 4;
        const float4* srcw = (const float4*)(w + (size_t)o0 * 2304);
#pragma unroll
        for (int i = 0; i < 5; ++i) {
            const int idx = t + 512 * i;
            if (idx < 2304) ((float4*)lw)[idx] = srcw[idx];
        }
        __syncthreads();
#pragma unroll
        for (int i = 0; i < 3; ++i) {
            const int u = t + 512 * i;            // 0..1151
            if (u < 1152) {
                const int o = u / 288, r = u - o * 288;
                const int kb2 = r >> 3, rr = r & 7;
                const int s = rr >> 2, qq = rr & 3;
                const int kk = kb2 >> 2, cp = kb2 & 3;
                f16x8 vv;
#pragma unroll
                for (int e = 0; e < 8; ++e) {
                    const int c = cp * 64 + s * 32 + qq * 8 + e;
                    vv[e] = (f16_t)lw[o * 2304 + c * 9 + kk];
                }
                *(f16x8*)(Wp + (size_t)kb2 * 16384 + s * 8192 + qq * 2048
                              + (size_t)(o0 + o) * 8) = vv;
            }
        }
    }
}

// ---------------------------------------------------------------------------
// Kernel 2: fused deformable-sample + GEMM, f16.  r5 skeleton (proven best:
// 60.1 us — 1 block/CU, 16 waves, reg-staged A into LDS once/iter = 96 KB
// vmem/iter/CU, conflict-free sA/sS, lgkm-only barriers) with ONE change:
// the post-MFMA sched_barrier(0) is removed, letting the combine VALU chain
// (register-independent of the MFMAs) interleave into the MFMA shadow —
// MFMA and VALU are separate pipes. The pre-MFMA sched_barrier stays: it is
// the proven protection against the compiler sinking the gather loads to
// their use (r1's 157-us failure mode).
// Grid 256: b = blk&7 (XCD pin), hb = blk>>3.
// ---------------------------------------------------------------------------
__global__ __launch_bounds__(1024, 4) void k_dcn(
    const f16_t* __restrict__ xt, const f16_t* __restrict__ Wp,
    const float* __restrict__ coff, const float* __restrict__ cwm,
    const float* __restrict__ bias, float* __restrict__ out) {

    __shared__ __align__(16) f16_t sS[2][128 * 64];   // 32 KB sampled tile
    __shared__ __align__(16) f16_t sA[2][16384];      // 64 KB A double-buffer
    __shared__ __align__(16) int2 sT[9 * 128 * 4];    // 36 KB corner table

    const int blk = blockIdx.x;
    const int b  = blk & 7;
    const int hb = blk >> 3;       // 0..31
    const int h0 = hb * 2;
    const int t = threadIdx.x;
    const int wv = t >> 6;         // 0..15
    const int lane = t & 63;
    const int mg = wv >> 1;        // 0..7 : M-group (32 O rows)
    const int ng = wv & 1;         // 0..1 : h-row

    const int p = t >> 3;          // 0..127 pixel (8 threads/pixel)
    const int q = t & 7;           // 8-channel slice

    const int fr = lane & 15;
    const int quad = lane >> 4;
    const int swz = fr & 7;

    // ---- precompute corner table: 9 taps x 128 px ----
    for (int u = t; u < 1152; u += 1024) {
        const int kk = u >> 7, pp = u & 127;
        const int hr = pp >> 6, wpx = pp & 63;
        const int h = h0 + hr;
        float oy = coff[((size_t)(b * 18 + kk * 2 + 0) * 64 + h) * 64 + wpx];
        float ox = coff[((size_t)(b * 18 + kk * 2 + 1) * 64 + h) * 64 + wpx];
        float m  = cwm [((size_t)(b * 9 + kk) * 64 + h) * 64 + wpx];
        float py = (float)(h - 1 + (kk / 3)) + oy;
        float px = (float)(wpx - 1 + (kk % 3)) + ox;
        float fy = floorf(py), fx = floorf(px);
        int y0 = (int)fy, x0 = (int)fx;
        int y1 = y0 + 1,  x1 = x0 + 1;
        float wy1 = py - fy, wx1 = px - fx;
        float wy0 = 1.0f - wy1, wx0 = 1.0f - wx1;
        bool vy0 = (y0 >= 0) && (y0 < 64), vy1 = (y1 >= 0) && (y1 < 64);
        bool vx0 = (x0 >= 0) && (x0 < 64), vx1 = (x1 >= 0) && (x1 < 64);
        int yc0 = min(max(y0, 0), 63), yc1 = min(max(y1, 0), 63);
        int xc0 = min(max(x0, 0), 63), xc1 = min(max(x1, 0), 63);
        const int base = b * 4096;
        float cw[4];
        int   ca[4];
        cw[0] = (vy0 && vx0) ? wy0 * wx0 * m : 0.0f;
        cw[1] = (vy0 && vx1) ? wy0 * wx1 * m : 0.0f;
        cw[2] = (vy1 && vx0) ? wy1 * wx0 * m : 0.0f;
        cw[3] = (vy1 && vx1) ? wy1 * wx1 * m : 0.0f;
        ca[0] = (base + yc0 * 64 + xc0) * 512;   // byte offsets (f16)
        ca[1] = (base + yc0 * 64 + xc1) * 512;
        ca[2] = (base + yc1 * 64 + xc0) * 512;
        ca[3] = (base + yc1 * 64 + xc1) * 512;
#pragma unroll
        for (int c = 0; c < 4; ++c) {
            unsigned short ws = __builtin_bit_cast(unsigned short, (f16_t)cw[c]);
            sT[(kk * 128 + pp) * 4 + c] = make_int2(ca[c], (int)ws);
        }
    }
    __syncthreads();

    f16_t* const swb0 = &sS[0][p * 64 + ((q ^ (p & 7)) * 8)];
    const int qb = q * 16;                       // byte offset of ch slice
    const char* xb = (const char*)xt;

    f32x4 acc[2][4] = {};
    f16x8 g0, g1, g2, g3;                        // in-flight gather regs
    f16x8 sld0, sld1;                            // in-flight A-stage regs
    int4 t0, t1;                                 // corner table (per kk)

    auto stage_load = [&](int it) {
        const f16_t* g = Wp + (size_t)it * 16384 + wv * 1024 + lane * 8;
        sld0 = *(const f16x8*)(g);
        sld1 = *(const f16x8*)(g + 512);
    };
    auto stage_write = [&](int buf) {
        f16_t* l = &sA[buf][wv * 1024 + lane * 8];
        *(f16x8*)(l)       = sld0;
        *(f16x8*)(l + 512) = sld1;
    };

    // issue-only half of the sample: table refresh (kk change) + 4 gathers
    auto gather_issue = [&](int it) {
        const int kk = it >> 2, cp = it & 3;
        if ((it & 3) == 0) {                     // uniform branch, every 4th
            const int4* tp = (const int4*)&sT[(kk * 128 + p) * 4];
            t0 = tp[0];                          // ds_read_b128 x2
            t1 = tp[1];
        }
        const int cb = cp * 128 + qb;
        g0 = *(const f16x8*)(xb + (t0.x + cb));
        g1 = *(const f16x8*)(xb + (t0.z + cb));
        g2 = *(const f16x8*)(xb + (t1.x + cb));
        g3 = *(const f16x8*)(xb + (t1.z + cb));
    };

    // combine-late: vmcnt wait lands just before first g-use; free to
    // interleave with the MFMA cluster (no SB0 between them any more).
    auto combine_write = [&](int buf) {
        f16_t w0 = __builtin_bit_cast(f16_t, (unsigned short)t0.y);
        f16_t w1 = __builtin_bit_cast(f16_t, (unsigned short)t0.w);
        f16_t w2 = __builtin_bit_cast(f16_t, (unsigned short)t1.y);
        f16_t w3 = __builtin_bit_cast(f16_t, (unsigned short)t1.w);
        f16x8 w0v = {w0, w0, w0, w0, w0, w0, w0, w0};
        f16x8 w1v = {w1, w1, w1, w1, w1, w1, w1, w1};
        f16x8 w2v = {w2, w2, w2, w2, w2, w2, w2, w2};
        f16x8 w3v = {w3, w3, w3, w3, w3, w3, w3, w3};
        f16x8 ov = g0 * w0v + g1 * w1v + g2 * w2v + g3 * w3v;
        *(f16x8*)(swb0 + buf * 8192) = ov;
    };

    auto do_mfma = [&](int cur) {
        const f16_t* sb = &sS[cur][ng * 4096];   // this wave's h-row tile
        // conflict-free fragment reads: lane byte = quad*4096+mg*512+fr*16
        const f16_t* sa = &sA[cur][quad * 2048 + mg * 256 + fr * 8];
        f16x8 aC[2][2];
        aC[0][0] = *(const f16x8*)(sa);
        aC[0][1] = *(const f16x8*)(sa + 8192);
        aC[1][0] = *(const f16x8*)(sa + 128);
        aC[1][1] = *(const f16x8*)(sa + 8192 + 128);
        __builtin_amdgcn_s_setprio(1);
#pragma unroll
        for (int s = 0; s < 2; ++s) {
            const int coffe = ((s * 4 + quad) ^ swz) * 8;
            f16x8 bb[4];
#pragma unroll
            for (int nt = 0; nt < 4; ++nt)
                bb[nt] = *(const f16x8*)(sb + (nt * 16 + fr) * 64 + coffe);
#pragma unroll
            for (int mt = 0; mt < 2; ++mt)
#pragma unroll
                for (int nt = 0; nt < 4; ++nt)
                    acc[mt][nt] = __builtin_amdgcn_mfma_f32_16x16x32_f16(
                        aC[mt][s], bb[nt], acc[mt][nt], 0, 0, 0);
        }
        __builtin_amdgcn_s_setprio(0);
    };

    // ---- prologue: stage tile 0 (samples + A) ----
    stage_load(0);
    gather_issue(0);
    combine_write(0);                            // vmcnt drain covers sld too
    stage_write(0);
    lgkm_barrier();

    // ---- main loop: 18 x 2 phases ----
    for (int it2 = 0; it2 < 36; it2 += 2) {
        // phase even: compute iter it2 (sS[0], sA[0]); prep it2+1
        stage_load(it2 + 1);
        gather_issue(it2 + 1);
        __builtin_amdgcn_sched_barrier(0);       // pin loads above MFMA
        do_mfma(0);
        combine_write(1);                        // may interleave with MFMA
        stage_write(1);
        lgkm_barrier();

        // phase odd: compute iter it2+1 (sS[1], sA[1]); prep it2+2
        const bool more = (it2 + 2) < 36;
        if (more) {
            stage_load(it2 + 2);
            gather_issue(it2 + 2);
        }
        __builtin_amdgcn_sched_barrier(0);
        do_mfma(1);
        if (more) {
            combine_write(0);
            stage_write(0);
        }
        lgkm_barrier();
    }

    // ---- epilogue: D layout col=lane&15 (px), row=(lane>>4)*4+r (O) ----
    const int rowq = quad * 4;
#pragma unroll
    for (int mt = 0; mt < 2; ++mt) {
#pragma unroll
        for (int r = 0; r < 4; ++r) {
            const int og = mg * 32 + mt * 16 + rowq + r;
            const float bs = bias[og];
            float* opn = out + ((size_t)(b * 256 + og) * 64 + (h0 + ng)) * 64;
#pragma unroll
            for (int nt = 0; nt < 4; ++nt) {
                opn[nt * 16 + fr] = acc[mt][nt][r] + bs;
            }
        }
    }
}

// ---------------------------------------------------------------------------
extern "C" void kernel_launch(void* const* d_in, const int* in_sizes, int n_in,
                              void* d_out, int out_size, void* d_ws, size_t ws_size,
                              hipStream_t stream) {
    const float* x    = (const float*)d_in[0];  // (8,256,64,64)
    const float* coff = (const float*)d_in[1];  // (8,18,64,64)
    const float* cwm  = (const float*)d_in[2];  // (8,9,64,64)
    const float* wgt  = (const float*)d_in[3];  // (256,256,3,3)
    const float* bias = (const float*)d_in[4];  // (256,)
    float* out = (float*)d_out;                 // (8,256,64,64)

    f16_t* xt = (f16_t*)d_ws;                   // 8*64*64*256 elems
    f16_t* Wp = xt + (size_t)8 * 64 * 64 * 256; // 36*16384 elems

    k_prep<<<576, 512, 0, stream>>>(x, wgt, xt, Wp);
    k_dcn <<<256, 1024, 0, stream>>>(xt, Wp, coff, cwm, bias, out);
}